// Round 1
// 917.172 us; speedup vs baseline: 1.0411x; 1.0411x over previous
//
#include <hip/hip_runtime.h>
#include <math.h>

#define C 128
#define B 4096
#define NNODES 500000
#define NOUT 4

// ---------------------------------------------------------------------------
// ws layout (fp32 elements):
//   A0   [B][256]   (cols 0:128 = h, cols 128:256 = r)  ping
//   A1   [B][256]                                        pong
//   c0   [B][128]
//   Wc   [512][256] channel-grouped combined weights (t>=1)
//   W0   [512][128] channel-grouped W_hh (t==0)
//   bp   [512]      channel-grouped b_ih+b_hh
//   sstart/send int[B]
// total ~11 MB
// ---------------------------------------------------------------------------

__global__ void init_state(const float* __restrict__ h, float* __restrict__ A0,
                           float* __restrict__ c0, int* __restrict__ sstart,
                           int* __restrict__ send) {
    int idx = blockIdx.x * blockDim.x + threadIdx.x;
    if (idx < B * 256) {
        int b = idx >> 8, cc = idx & 255;
        A0[idx] = (cc < C) ? h[b * C + cc] : 0.f;
    }
    if (idx < B * C) c0[idx] = h[idx];
    if (idx < B) { sstart[idx] = 0; send[idx] = 0; }
}

// Reorder W rows to channel-major (n = 4c + gate) and fold W_ih[:, :C] + W_hh
// (valid because for t>=1 the GEMM input cols [0:C) and [2C:3C) are identical h).
__global__ void prep_w(const float* __restrict__ W_ih, const float* __restrict__ W_hh,
                       const float* __restrict__ b_ih, const float* __restrict__ b_hh,
                       float* __restrict__ Wc, float* __restrict__ W0,
                       float* __restrict__ bp) {
    int idx = blockIdx.x * blockDim.x + threadIdx.x;   // 512*256
    int n = idx >> 8, kk = idx & 255;
    int c = n >> 2, gi = n & 3;
    int j = gi * C + c;                                 // original gate-row index
    float wih = W_ih[(size_t)j * 256 + kk];
    float val = (kk < C) ? (wih + W_hh[(size_t)j * C + kk]) : wih;
    Wc[(size_t)n * 256 + kk] = val;
    if (kk < C) W0[(size_t)n * C + kk] = W_hh[(size_t)j * C + kk];
    if (kk == 0) bp[n] = b_ih[j] + b_hh[j];
}

__global__ void seg_bounds(const int* __restrict__ batch, int* __restrict__ sstart,
                           int* __restrict__ send) {
    int n = blockIdx.x * blockDim.x + threadIdx.x;
    if (n >= NNODES) return;
    int b = batch[n];
    if (n == 0 || batch[n - 1] != b) sstart[b] = n;
    if (n == NNODES - 1 || batch[n + 1] != b) send[b] = n + 1;
}

// ---------------------------------------------------------------------------
// Fused LSTM: gates GEMM (A[B][256] x W^T, channel-grouped N) + activation
// epilogue. BM=128, BN=64, BK=16, 256 threads, 8x4 acc per thread.
// Each thread's 4 cols = {i,f,g,o} of one channel -> LSTM math in-register,
// h written to Anx (ping-pong), c0 updated in place (unique owner per (b,c)).
// ---------------------------------------------------------------------------
#define GBM 128
#define GBN 64
#define GBK 16

__global__ __launch_bounds__(256) void lstm_fused(
    const float* __restrict__ A, const float* __restrict__ W,
    const float* __restrict__ bp, float* __restrict__ c0,
    float* __restrict__ Anx, int Klen, int ldw) {
    __shared__ float As[GBK][132];
    __shared__ float Bs[GBK][68];
    const int bm0 = blockIdx.x * GBM;
    const int jn0 = blockIdx.y * GBN;
    const int tid = threadIdx.x;
    const int tx = tid & 15, ty = tid >> 4;
    const int sr = tid >> 2, sk = (tid & 3) << 2;

    float acc[8][4];
#pragma unroll
    for (int i = 0; i < 8; ++i)
#pragma unroll
        for (int q = 0; q < 4; ++q) acc[i][q] = 0.f;

    for (int k0 = 0; k0 < Klen; k0 += GBK) {
        const float4 a0 = *(const float4*)(A + (size_t)(bm0 + sr) * 256 + k0 + sk);
        const float4 a1 = *(const float4*)(A + (size_t)(bm0 + 64 + sr) * 256 + k0 + sk);
        const float4 bv = *(const float4*)(W + (size_t)(jn0 + sr) * ldw + k0 + sk);
        __syncthreads();
        As[sk + 0][sr] = a0.x; As[sk + 1][sr] = a0.y;
        As[sk + 2][sr] = a0.z; As[sk + 3][sr] = a0.w;
        As[sk + 0][64 + sr] = a1.x; As[sk + 1][64 + sr] = a1.y;
        As[sk + 2][64 + sr] = a1.z; As[sk + 3][64 + sr] = a1.w;
        Bs[sk + 0][sr] = bv.x; Bs[sk + 1][sr] = bv.y;
        Bs[sk + 2][sr] = bv.z; Bs[sk + 3][sr] = bv.w;
        __syncthreads();
#pragma unroll
        for (int kk = 0; kk < GBK; ++kk) {
            const float4 af0 = *(const float4*)&As[kk][ty << 3];
            const float4 af1 = *(const float4*)&As[kk][(ty << 3) + 4];
            const float4 bf  = *(const float4*)&Bs[kk][tx << 2];
            const float aa[8] = {af0.x, af0.y, af0.z, af0.w, af1.x, af1.y, af1.z, af1.w};
            const float bb[4] = {bf.x, bf.y, bf.z, bf.w};
#pragma unroll
            for (int i = 0; i < 8; ++i)
#pragma unroll
                for (int q = 0; q < 4; ++q)
                    acc[i][q] = fmaf(aa[i], bb[q], acc[i][q]);
        }
    }

    // epilogue: cols (jn0+4tx .. +3) = gates {i,f,g,o} of channel c
    const int c = (jn0 >> 2) + tx;
    const float4 bb4 = *(const float4*)(bp + jn0 + (tx << 2));
#pragma unroll
    for (int i = 0; i < 8; ++i) {
        const int b = bm0 + (ty << 3) + i;
        const float gi = acc[i][0] + bb4.x;
        const float gf = acc[i][1] + bb4.y;
        const float gg = acc[i][2] + bb4.z;
        const float go = acc[i][3] + bb4.w;
        const float si = 1.f / (1.f + __expf(-gi));
        const float sf = 1.f / (1.f + __expf(-gf));
        const float so = 1.f / (1.f + __expf(-go));
        const float tg = tanhf(gg);
        const float cn = sf * c0[(size_t)b * C + c] + si * tg;
        const float hn = so * tanhf(cn);
        c0[(size_t)b * C + c] = cn;
        Anx[(size_t)b * 256 + c] = hn;
    }
}

// ---------------------------------------------------------------------------
// Single-pass flash-style segment attention. One block (4 waves) per segment.
// Lane layout: g = lane>>4 (node within pack), j = lane&15, 8 channels/lane.
// Main loop: 8 nodes/wave-iter, k AND v loaded together (8x dwordx4 in
// flight), online (m,s) + rescaled accumulator. No e_ws scratch, no second
// pass, no mid-kernel drain points. Guard-free main loop + guarded tail.
// ---------------------------------------------------------------------------
__device__ __forceinline__ float dot8(const float4 a0, const float4 a1,
                                      const float4 q0, const float4 q1) {
    float p = a0.x * q0.x + a0.y * q0.y + a0.z * q0.z + a0.w * q0.w;
    p += a1.x * q1.x + a1.y * q1.y + a1.z * q1.z + a1.w * q1.w;
    return p;
}

__global__ __launch_bounds__(256) void attention(
    const float* __restrict__ k, const float* __restrict__ v,
    float* __restrict__ Anx, const int* __restrict__ sstart,
    const int* __restrict__ send, float* __restrict__ out, int t) {
    const int b = blockIdx.x;
    const int tid = threadIdx.x;
    const int w = tid >> 6, lane = tid & 63, g = lane >> 4, j = lane & 15;
    const int ch = j << 3;

    __shared__ float mred[4], sred[4];
    __shared__ float racc[16][C];

    const int s0 = sstart[b], s1 = send[b];
    const int full = (s1 - s0) & ~31;
    const int sf = s0 + full;

    const float4 qa = *(const float4*)(Anx + (size_t)b * 256 + ch);
    const float4 qb = *(const float4*)(Anx + (size_t)b * 256 + ch + 4);

    float m = -3.0e38f, s = 0.f;   // finite lowest: empty groups stay NaN-free
    float4 r0 = {0.f, 0.f, 0.f, 0.f}, r1 = {0.f, 0.f, 0.f, 0.f};

    // main: 8 nodes per wave-iter, no guard
    for (int n0 = s0 + (w << 3); n0 < sf; n0 += 32) {
        const int na = n0 + g, nb = na + 4;
        const float4 ka0 = *(const float4*)(k + (size_t)na * C + ch);
        const float4 ka1 = *(const float4*)(k + (size_t)na * C + ch + 4);
        const float4 kb0 = *(const float4*)(k + (size_t)nb * C + ch);
        const float4 kb1 = *(const float4*)(k + (size_t)nb * C + ch + 4);
        const float4 va0 = *(const float4*)(v + (size_t)na * C + ch);
        const float4 va1 = *(const float4*)(v + (size_t)na * C + ch + 4);
        const float4 vb0 = *(const float4*)(v + (size_t)nb * C + ch);
        const float4 vb1 = *(const float4*)(v + (size_t)nb * C + ch + 4);
        float pa = dot8(ka0, ka1, qa, qb);
        float pb = dot8(kb0, kb1, qa, qb);
        pa += __shfl_xor(pa, 1); pb += __shfl_xor(pb, 1);
        pa += __shfl_xor(pa, 2); pb += __shfl_xor(pb, 2);
        pa += __shfl_xor(pa, 4); pb += __shfl_xor(pb, 4);
        pa += __shfl_xor(pa, 8); pb += __shfl_xor(pb, 8);
        const float mn = fmaxf(m, fmaxf(pa, pb));
        const float ef = __expf(m - mn);
        const float wa = __expf(pa - mn);
        const float wb = __expf(pb - mn);
        s = s * ef + wa + wb;
        m = mn;
        r0.x = fmaf(wb, vb0.x, fmaf(wa, va0.x, r0.x * ef));
        r0.y = fmaf(wb, vb0.y, fmaf(wa, va0.y, r0.y * ef));
        r0.z = fmaf(wb, vb0.z, fmaf(wa, va0.z, r0.z * ef));
        r0.w = fmaf(wb, vb0.w, fmaf(wa, va0.w, r0.w * ef));
        r1.x = fmaf(wb, vb1.x, fmaf(wa, va1.x, r1.x * ef));
        r1.y = fmaf(wb, vb1.y, fmaf(wa, va1.y, r1.y * ef));
        r1.z = fmaf(wb, vb1.z, fmaf(wa, va1.z, r1.z * ef));
        r1.w = fmaf(wb, vb1.w, fmaf(wa, va1.w, r1.w * ef));
    }
    // tail: 4 nodes per wave-iter, guarded (uniform per 16-lane group)
    for (int n0 = sf + (w << 2); n0 < s1; n0 += 16) {
        const int n = n0 + g;
        if (n < s1) {
            const float4 ka0 = *(const float4*)(k + (size_t)n * C + ch);
            const float4 ka1 = *(const float4*)(k + (size_t)n * C + ch + 4);
            const float4 va0 = *(const float4*)(v + (size_t)n * C + ch);
            const float4 va1 = *(const float4*)(v + (size_t)n * C + ch + 4);
            float p = dot8(ka0, ka1, qa, qb);
            p += __shfl_xor(p, 1);
            p += __shfl_xor(p, 2);
            p += __shfl_xor(p, 4);
            p += __shfl_xor(p, 8);
            const float mn = fmaxf(m, p);
            const float ef = __expf(m - mn);
            const float wa = __expf(p - mn);
            s = s * ef + wa;
            m = mn;
            r0.x = fmaf(wa, va0.x, r0.x * ef);
            r0.y = fmaf(wa, va0.y, r0.y * ef);
            r0.z = fmaf(wa, va0.z, r0.z * ef);
            r0.w = fmaf(wa, va0.w, r0.w * ef);
            r1.x = fmaf(wa, va1.x, r1.x * ef);
            r1.y = fmaf(wa, va1.y, r1.y * ef);
            r1.z = fmaf(wa, va1.z, r1.z * ef);
            r1.w = fmaf(wa, va1.w, r1.w * ef);
        }
    }

    // merge (m,s) across the 4 groups of the wave (butterfly over bits 4,5)
    float mw = m, sw = s;
#pragma unroll
    for (int off = 16; off <= 32; off <<= 1) {
        const float om = __shfl_xor(mw, off);
        const float os = __shfl_xor(sw, off);
        const float mn = fmaxf(mw, om);
        sw = sw * __expf(mw - mn) + os * __expf(om - mn);
        mw = mn;
    }
    if (lane == 0) { mred[w] = mw; sred[w] = sw; }
    __syncthreads();
    const float M = fmaxf(fmaxf(mred[0], mred[1]), fmaxf(mred[2], mred[3]));
    const float S = sred[0] * __expf(mred[0] - M) + sred[1] * __expf(mred[1] - M)
                  + sred[2] * __expf(mred[2] - M) + sred[3] * __expf(mred[3] - M);
    const float inv = 1.f / (S + 1e-16f);

    // scale group-local accumulator to global max and reduce
    const float sc = __expf(m - M) * inv;
    float4 w0 = r0, w1 = r1;
    w0.x *= sc; w0.y *= sc; w0.z *= sc; w0.w *= sc;
    w1.x *= sc; w1.y *= sc; w1.z *= sc; w1.w *= sc;
    *(float4*)&racc[(w << 2) + g][ch]     = w0;
    *(float4*)&racc[(w << 2) + g][ch + 4] = w1;
    __syncthreads();

    if (tid < C) {
        float r = 0.f;
#pragma unroll
        for (int p = 0; p < 16; ++p) r += racc[p][tid];
        out[(size_t)b * (NOUT * C) + t * C + tid] = r;
        Anx[(size_t)b * 256 + C + tid] = r;
    }
}

// ---------------------------------------------------------------------------
extern "C" void kernel_launch(void* const* d_in, const int* in_sizes, int n_in,
                              void* d_out, int out_size, void* d_ws, size_t ws_size,
                              hipStream_t stream) {
    const float* k    = (const float*)d_in[0];
    const float* v    = (const float*)d_in[1];
    const float* h    = (const float*)d_in[2];
    const float* W_ih = (const float*)d_in[3];
    const float* W_hh = (const float*)d_in[4];
    const float* b_ih = (const float*)d_in[5];
    const float* b_hh = (const float*)d_in[6];
    const int*   batch = (const int*)d_in[7];
    float* out = (float*)d_out;

    float* ws  = (float*)d_ws;
    float* A0v = ws;                          // B*256
    float* A1v = A0v + (size_t)B * 256;       // B*256
    float* c0  = A1v + (size_t)B * 256;       // B*C
    float* Wc  = c0 + (size_t)B * C;          // 512*256
    float* W0  = Wc + 512 * 256;              // 512*128
    float* bp  = W0 + 512 * C;                // 512
    int* sstart = (int*)(bp + 512);
    int* send   = sstart + B;

    init_state<<<(B * 256 + 255) / 256, 256, 0, stream>>>(h, A0v, c0, sstart, send);
    prep_w<<<(512 * 256) / 256, 256, 0, stream>>>(W_ih, W_hh, b_ih, b_hh, Wc, W0, bp);
    seg_bounds<<<(NNODES + 255) / 256, 256, 0, stream>>>(batch, sstart, send);

    float* Abuf[2] = {A0v, A1v};
    for (int t = 0; t < NOUT; ++t) {
        const float* Acur = Abuf[t & 1];
        float* Anx = Abuf[(t + 1) & 1];
        if (t == 0)
            lstm_fused<<<dim3(B / GBM, 512 / GBN), 256, 0, stream>>>(
                Acur, W0, bp, c0, Anx, C, C);
        else
            lstm_fused<<<dim3(B / GBM, 512 / GBN), 256, 0, stream>>>(
                Acur, Wc, bp, c0, Anx, 256, 256);
        attention<<<B, 256, 0, stream>>>(k, v, Anx, sstart, send, out, t);
    }
}